// Round 19
// baseline (579.609 us; speedup 1.0000x reference)
//
#include <hip/hip_runtime.h>
#include <cmath>

#define NS 16384   // samples
#define LS 4096    // memory slots
#define DF 1024    // feature dim
#define SHRINK_T 0.0025f
#define EPS_T 1e-12f

using f16 = _Float16;
using f16x8 = __attribute__((ext_vector_type(8))) _Float16;
using f32x16 = __attribute__((ext_vector_type(16))) float;

#define NSEG 64   // centroid partial segments
#define BM 128
#define BN 128
#define BK 32
#define NKT (DF / BK)   // 32 k-tiles

// ---------------- K_pack: f32 -> f16 hi/lo in GEMM-packed plane layout ----------------
__global__ __launch_bounds__(256) void pack_kernel(
    const float* __restrict__ src, f16* __restrict__ ph, f16* __restrict__ pl)
{
    __shared__ f16 sh[4096];
    __shared__ f16 sl[4096];
    const int t = threadIdx.x;
    const int kt = blockIdx.x;
    const int R = blockIdx.y;
    const int r = t >> 1;           // 0..127
    const int half = t & 1;         // which 16-f32 half of the 32-col slice

    const float* s = src + (size_t)(R * 128 + r) * DF + kt * 32 + half * 16;
    float v[16];
#pragma unroll
    for (int q = 0; q < 4; ++q) {
        float4 f = ((const float4*)s)[q];
        v[q * 4 + 0] = f.x; v[q * 4 + 1] = f.y; v[q * 4 + 2] = f.z; v[q * 4 + 3] = f.w;
    }
    f16 h[16], l[16];
#pragma unroll
    for (int q = 0; q < 16; ++q) {
        h[q] = (f16)v[q];
        l[q] = (f16)(v[q] - (float)h[q]);
    }
    const int j0 = (half * 2) * 1024 + r * 8;
    const int j1 = j0 + 1024;
#pragma unroll
    for (int e = 0; e < 8; ++e) {
        sh[j0 + e] = h[e];     sl[j0 + e] = l[e];
        sh[j1 + e] = h[8 + e]; sl[j1 + e] = l[8 + e];
    }
    __syncthreads();
    const size_t og = ((size_t)R * NKT + kt) * 4096;
    *(f16x8*)&ph[og + t * 8]        = *(const f16x8*)&sh[t * 8];
    *(f16x8*)&ph[og + 2048 + t * 8] = *(const f16x8*)&sh[2048 + t * 8];
    *(f16x8*)&pl[og + t * 8]        = *(const f16x8*)&sl[t * 8];
    *(f16x8*)&pl[og + 2048 + t * 8] = *(const f16x8*)&sl[2048 + t * 8];
}

// ---------------- K0: centroid, two-stage deterministic ----------------
__global__ void centroid_part_kernel(const float* __restrict__ w, float* __restrict__ part) {
    const int c = blockIdx.x * 256 + threadIdx.x;
    const int seg = blockIdx.y;
    const int l0 = seg * (LS / NSEG);
    float acc = 0.f;
    for (int l = 0; l < LS / NSEG; ++l)
        acc += w[(size_t)(l0 + l) * DF + c];
    part[(size_t)seg * DF + c] = acc;
}

__global__ void centroid_sum_kernel(const float* __restrict__ part, float* __restrict__ cen) {
    const int c = blockIdx.x * 256 + threadIdx.x;
    float acc = 0.f;
    for (int s = 0; s < NSEG; ++s) acc += part[(size_t)s * DF + c];
    cen[c] = acc * (1.0f / (float)LS);
}

// ---------------- K1: S = x @ w^T, 3-term f16-split, 32x32x16 MFMA ----------------
// r16 champion (packed-plane staging, conflict-free LDS reads, 2 barriers/kt,
// reg-fragment prefetch) + T1 bijective XCD-chunked block swizzle: each XCD
// gets a contiguous run of row-panels -> A panel stays L2-resident, B panel
// re-reads become L2/L3 hits, cutting HBM over-fetch (measured 360 MB vs
// 84 MB of packed inputs).
#define GLOAD16(gptr, lptr)                                                    \
    __builtin_amdgcn_global_load_lds(                                          \
        (const __attribute__((address_space(1))) void*)(gptr),                 \
        (__attribute__((address_space(3))) void*)(lptr), 16, 0, 0)

__global__ __launch_bounds__(256) void gemm_f16_kernel(
    const f16* __restrict__ xph, const f16* __restrict__ xpl,
    const f16* __restrict__ wph, const f16* __restrict__ wpl,
    float* __restrict__ S, int r0, int rowsChunk)
{
    __shared__ __align__(16) f16 Ah[4096];   // plane image, 8 KB
    __shared__ __align__(16) f16 Al[4096];
    __shared__ __align__(16) f16 Bh[4096];
    __shared__ __align__(16) f16 Bl[4096];

    const int t = threadIdx.x;
    const int lane = t & 63;
    const int wv = t >> 6;                 // wave id 0..3
    const int wr = (wv >> 1) * 64;         // wave row offset in tile
    const int wc = (wv & 1) * 64;          // wave col offset in tile

    // ---- bijective XCD-chunked swizzle (identity if nwg % 8 != 0) ----
    const int nwg = gridDim.x * gridDim.y;
    const int wgid = blockIdx.y * gridDim.x + blockIdx.x;
    int nid = wgid;
    if ((nwg & 7) == 0) {
        const int cpx = nwg >> 3;          // blocks per XCD chunk
        nid = (wgid & 7) * cpx + (wgid >> 3);
    }
    const int bx = nid % gridDim.x;        // col-block
    const int by = nid / gridDim.x;        // row-block

    f32x16 acc[2][2];
#pragma unroll
    for (int m = 0; m < 2; ++m)
#pragma unroll
        for (int n = 0; n < 2; ++n)
#pragma unroll
            for (int j = 0; j < 16; ++j) acc[m][n][j] = 0.f;

    const int c32 = lane & 31;             // row/col within a 32x32 frag
    const int kh = lane >> 5;              // k-half -> plane parity

    const size_t atile = ((size_t)((r0 >> 7) + by)) * NKT;
    const size_t btile = ((size_t)bx) * NKT;
    const int lb0 = wv * 512;              // f16 offset, issue0
    const int lb1 = 2048 + wv * 512;       // issue1

#define STAGE(kt)                                                          \
    do {                                                                   \
        const size_t _a = (atile + (kt)) * 4096 + t * 8;                   \
        const size_t _b = (btile + (kt)) * 4096 + t * 8;                   \
        GLOAD16(xph + _a,        &Ah[lb0]);                                \
        GLOAD16(xph + _a + 2048, &Ah[lb1]);                                \
        GLOAD16(xpl + _a,        &Al[lb0]);                                \
        GLOAD16(xpl + _a + 2048, &Al[lb1]);                                \
        GLOAD16(wph + _b,        &Bh[lb0]);                                \
        GLOAD16(wph + _b + 2048, &Bh[lb1]);                                \
        GLOAD16(wpl + _b,        &Bl[lb0]);                                \
        GLOAD16(wpl + _b + 2048, &Bl[lb1]);                                \
    } while (0)

    STAGE(0);

    for (int kt = 0; kt < NKT; ++kt) {
        // barrier #1: implicit vmcnt(0) — kt's DMA issued a full MFMA phase ago.
        __syncthreads();

        // ---- all fragments of kt -> registers (16 x ds_read_b128, zero
        //      bank conflicts — r13/r16-proven plane layout) ----
        f16x8 amh[2][2], aml[2][2], bnh[2][2], bnl[2][2];  // [slice][frag]
#pragma unroll
        for (int s = 0; s < 2; ++s) {
            const int pl = s * 2 + kh;     // plane
#pragma unroll
            for (int m = 0; m < 2; ++m) {
                const int j = pl * 1024 + (wr + m * 32 + c32) * 8;
                amh[s][m] = *(const f16x8*)&Ah[j];
                aml[s][m] = *(const f16x8*)&Al[j];
            }
#pragma unroll
            for (int n = 0; n < 2; ++n) {
                const int j = pl * 1024 + (wc + n * 32 + c32) * 8;
                bnh[s][n] = *(const f16x8*)&Bh[j];
                bnl[s][n] = *(const f16x8*)&Bl[j];
            }
        }

        // barrier #2: implicit lgkmcnt(0) — all waves done reading; LDS free.
        __syncthreads();
        if (kt + 1 < NKT) STAGE(kt + 1);   // DMA flies under the MFMAs

        // ---- 24 MFMA on registers ----
#pragma unroll
        for (int s = 0; s < 2; ++s)
#pragma unroll
            for (int m = 0; m < 2; ++m)
#pragma unroll
                for (int n = 0; n < 2; ++n) {
                    acc[m][n] = __builtin_amdgcn_mfma_f32_32x32x16_f16(amh[s][m], bnh[s][n], acc[m][n], 0, 0, 0);
                    acc[m][n] = __builtin_amdgcn_mfma_f32_32x32x16_f16(amh[s][m], bnl[s][n], acc[m][n], 0, 0, 0);
                    acc[m][n] = __builtin_amdgcn_mfma_f32_32x32x16_f16(aml[s][m], bnh[s][n], acc[m][n], 0, 0, 0);
                }
    }
#undef STAGE

    // C write: col = lane&31, row = (reg&3) + 8*(reg>>2) + 4*(lane>>5)  [m74/m101]
#pragma unroll
    for (int m = 0; m < 2; ++m) {
        const int rb = by * BM + wr + m * 32 + 4 * kh;   // chunk-local
#pragma unroll
        for (int n = 0; n < 2; ++n) {
            const int cc = bx * BN + wc + n * 32 + c32;
#pragma unroll
            for (int reg = 0; reg < 16; ++reg) {
                const int rr = rb + (reg & 3) + 8 * (reg >> 2);
                if (rr < rowsChunk)
                    S[(size_t)rr * LS + cc] = acc[m][n][reg];
            }
        }
    }
}

// ---------------- K2: per-row softmax/shrink/norm + all outputs (float4) ----------------
__global__ __launch_bounds__(256) void pass2_kernel(
    const float* __restrict__ S, const float* __restrict__ x,
    const float* __restrict__ w, const float* __restrict__ cen,
    float* __restrict__ out, int r0)
{
    constexpr int T = 256;
    __shared__ __align__(16) float att_lds[LS];
    __shared__ float red[T];
    __shared__ int redi[T];

    const int t = threadIdx.x;
    const size_t row = (size_t)r0 + blockIdx.x;
    const float4* s4 = (const float4*)(S + (size_t)blockIdx.x * (size_t)LS);

    float* const out_output = out;
    float* const out_att  = out + (size_t)NS * DF;
    float* const out_nl   = out + (size_t)NS * DF + (size_t)NS * LS;
    float* const out_nl2  = out + (size_t)2 * NS * DF + (size_t)NS * LS;
    float* const out_mask = out + (size_t)3 * NS * DF + (size_t)NS * LS;

    float sv[16];
    float mx = -INFINITY;
#pragma unroll
    for (int i = 0; i < 4; ++i) {
        float4 v = s4[i * 256 + t];
        sv[i * 4 + 0] = v.x; sv[i * 4 + 1] = v.y;
        sv[i * 4 + 2] = v.z; sv[i * 4 + 3] = v.w;
        mx = fmaxf(mx, fmaxf(fmaxf(v.x, v.y), fmaxf(v.z, v.w)));
    }
    red[t] = mx;
    __syncthreads();
    for (int off = 128; off >= 1; off >>= 1) {
        if (t < off) red[t] = fmaxf(red[t], red[t + off]);
        __syncthreads();
    }
    const float m = red[0];
    __syncthreads();

    float zs = 0.f;
#pragma unroll
    for (int i = 0; i < 16; ++i) {
        sv[i] = expf(sv[i] - m);
        zs += sv[i];
    }
    red[t] = zs;
    __syncthreads();
    for (int off = 128; off >= 1; off >>= 1) {
        if (t < off) red[t] += red[t + off];
        __syncthreads();
    }
    const float Z = red[0];
    __syncthreads();

    float l1 = 0.f;
#pragma unroll
    for (int i = 0; i < 16; ++i) {
        float a = sv[i] / Z;
        float r = a - SHRINK_T;
        float v = (r > 0.f) ? (r * a) / (r + EPS_T) : 0.f;
        sv[i] = v;
        l1 += v;
    }
    red[t] = l1;
    __syncthreads();
    for (int off = 128; off >= 1; off >>= 1) {
        if (t < off) red[t] += red[t + off];
        __syncthreads();
    }
    const float nrm = fmaxf(red[0], EPS_T);
    __syncthreads();

    float bv = -INFINITY; int bi = LS;
    float mn = INFINITY;
    float4* const attl4 = (float4*)att_lds;
    float4* const att4o = (float4*)(out_att + row * LS);
#pragma unroll
    for (int i = 0; i < 4; ++i) {
        float4 vn4;
        vn4.x = sv[i * 4 + 0] / nrm; vn4.y = sv[i * 4 + 1] / nrm;
        vn4.z = sv[i * 4 + 2] / nrm; vn4.w = sv[i * 4 + 3] / nrm;
        sv[i * 4 + 0] = vn4.x; sv[i * 4 + 1] = vn4.y;
        sv[i * 4 + 2] = vn4.z; sv[i * 4 + 3] = vn4.w;
        attl4[i * 256 + t] = vn4;
        att4o[i * 256 + t] = vn4;
#pragma unroll
        for (int c = 0; c < 4; ++c) {
            const float v = sv[i * 4 + c];
            const int j = i * 1024 + 4 * t + c;
            if (v > bv) { bv = v; bi = j; }
            mn = fminf(mn, v);
        }
    }
    __syncthreads();

    red[t] = bv; redi[t] = bi;
    __syncthreads();
    for (int off = 128; off >= 1; off >>= 1) {
        if (t < off) {
            float ov = red[t + off]; int oi = redi[t + off];
            if (ov > red[t] || (ov == red[t] && oi < redi[t])) { red[t] = ov; redi[t] = oi; }
        }
        __syncthreads();
    }
    const int ind = redi[0];
    __syncthreads();

    red[t] = mn;
    __syncthreads();
    for (int off = 128; off >= 1; off >>= 1) {
        if (t < off) red[t] = fminf(red[t], red[t + off]);
        __syncthreads();
    }
    const float rowmin = red[0];
    __syncthreads();

    bv = -INFINITY; bi = LS;
#pragma unroll
    for (int i = 0; i < 4; ++i)
#pragma unroll
        for (int c = 0; c < 4; ++c) {
            const int j = i * 1024 + 4 * t + c;
            const float vv = (j == ind) ? rowmin : sv[i * 4 + c];
            if (vv > bv) { bv = vv; bi = j; }
        }
    red[t] = bv; redi[t] = bi;
    __syncthreads();
    for (int off = 128; off >= 1; off >>= 1) {
        if (t < off) {
            float ov = red[t + off]; int oi = redi[t + off];
            if (ov > red[t] || (ov == red[t] && oi < redi[t])) { red[t] = ov; redi[t] = oi; }
        }
        __syncthreads();
    }
    const int ind2 = redi[0];
    __syncthreads();

    const int lane = t & 63;
    float4 oa = {0.f, 0.f, 0.f, 0.f};
    for (int k0 = 0; k0 < LS; k0 += 64) {
        float av = att_lds[k0 + lane];
        unsigned long long msk = __ballot(av > 0.f);
        while (msk) {
            int b = __ffsll((unsigned long long)msk) - 1;
            msk &= msk - 1;
            float vv = att_lds[k0 + b];
            float4 wv4 = ((const float4*)(w + (size_t)(k0 + b) * DF))[t];
            oa.x = fmaf(vv, wv4.x, oa.x);
            oa.y = fmaf(vv, wv4.y, oa.y);
            oa.z = fmaf(vv, wv4.z, oa.z);
            oa.w = fmaf(vv, wv4.w, oa.w);
        }
    }
    ((float4*)(out_output + row * DF))[t] = oa;

    ((float4*)(out_nl  + row * DF))[t] = ((const float4*)(w + (size_t)ind  * DF))[t];
    ((float4*)(out_nl2 + row * DF))[t] = ((const float4*)(w + (size_t)ind2 * DF))[t];

    float4 xv = ((const float4*)(x + row * DF))[t];
    float4 cv = ((const float4*)cen)[t];
    float ds = 0.f;
    ds = fmaf(xv.x - cv.x, xv.x - cv.x, ds);
    ds = fmaf(xv.y - cv.y, xv.y - cv.y, ds);
    ds = fmaf(xv.z - cv.z, xv.z - cv.z, ds);
    ds = fmaf(xv.w - cv.w, xv.w - cv.w, ds);
    red[t] = ds;
    __syncthreads();
    for (int off = 128; off >= 1; off >>= 1) {
        if (t < off) red[t] += red[t + off];
        __syncthreads();
    }
    if (t == 0) {
        float dist = sqrtf(red[0]);
        out_mask[row] = (dist < 1.0f) ? 1.0f : 0.0f;
    }
}

// ---------------- host ----------------
extern "C" void kernel_launch(void* const* d_in, const int* in_sizes, int n_in,
                              void* d_out, int out_size, void* d_ws, size_t ws_size,
                              hipStream_t stream)
{
    const float* x = (const float*)d_in[0];
    const float* w = (const float*)d_in[1];
    float* out = (float*)d_out;

    // workspace layout: cen | partial | xph | xpl | wph | wpl | S
    float* cen = (float*)d_ws;
    float* part = cen + DF;
    f16* xph = (f16*)(part + (size_t)NSEG * DF);
    f16* xpl = xph + (size_t)NS * DF;
    f16* wph = xpl + (size_t)NS * DF;
    f16* wpl = wph + (size_t)LS * DF;
    float* S = (float*)(wpl + (size_t)LS * DF);

    const size_t head_bytes = sizeof(float) * (DF + (size_t)NSEG * DF)
                            + (size_t)2 * 2 * NS * DF + (size_t)2 * 2 * LS * DF;
    long cap_rows = (long)((ws_size - head_bytes) / (sizeof(float) * LS));
    if (cap_rows > NS) cap_rows = NS;
    if (cap_rows < 1) cap_rows = 1;
    int chunk = (cap_rows >= BM) ? (int)(cap_rows - (cap_rows % BM)) : (int)cap_rows;

    centroid_part_kernel<<<dim3(DF / 256, NSEG), 256, 0, stream>>>(w, part);
    centroid_sum_kernel<<<DF / 256, 256, 0, stream>>>(part, cen);
    pack_kernel<<<dim3(NKT, NS / 128), 256, 0, stream>>>(x, xph, xpl);
    pack_kernel<<<dim3(NKT, LS / 128), 256, 0, stream>>>(w, wph, wpl);

    for (int r0 = 0; r0 < NS; r0 += chunk) {
        int rows = (NS - r0 < chunk) ? (NS - r0) : chunk;
        dim3 grid(LS / BN, (rows + BM - 1) / BM);
        gemm_f16_kernel<<<grid, 256, 0, stream>>>(xph, xpl, wph, wpl, S, r0, rows);
        pass2_kernel<<<rows, 256, 0, stream>>>(S, x, w, cen, out, r0);
    }
}

// Round 20
// 557.703 us; speedup vs baseline: 1.0393x; 1.0393x over previous
//
#include <hip/hip_runtime.h>
#include <cmath>

#define NS 16384   // samples
#define LS 4096    // memory slots
#define DF 1024    // feature dim
#define SHRINK_T 0.0025f
#define EPS_T 1e-12f

using f16 = _Float16;
using f16x8 = __attribute__((ext_vector_type(8))) _Float16;
using f32x16 = __attribute__((ext_vector_type(16))) float;

#define NSEG 64   // centroid partial segments
#define BM 128
#define BN 128
#define BK 32
#define NKT (DF / BK)   // 32 k-tiles
// packed tile: per (row-block of 128, k-tile of 32): plane image
// [p=0..3][r=0..127][e=0..7]  (4096 f16 = 8 KB), tiles consecutive.

// ---------------- K_pack: f32 -> f16 hi/lo in GEMM-packed plane layout ----------------
__global__ __launch_bounds__(256) void pack_kernel(
    const float* __restrict__ src, f16* __restrict__ ph, f16* __restrict__ pl)
{
    __shared__ f16 sh[4096];
    __shared__ f16 sl[4096];
    const int t = threadIdx.x;
    const int kt = blockIdx.x;
    const int R = blockIdx.y;
    const int r = t >> 1;           // 0..127
    const int half = t & 1;         // which 16-f32 half of the 32-col slice

    const float* s = src + (size_t)(R * 128 + r) * DF + kt * 32 + half * 16;
    float v[16];
#pragma unroll
    for (int q = 0; q < 4; ++q) {
        float4 f = ((const float4*)s)[q];
        v[q * 4 + 0] = f.x; v[q * 4 + 1] = f.y; v[q * 4 + 2] = f.z; v[q * 4 + 3] = f.w;
    }
    f16 h[16], l[16];
#pragma unroll
    for (int q = 0; q < 16; ++q) {
        h[q] = (f16)v[q];
        l[q] = (f16)(v[q] - (float)h[q]);
    }
    const int j0 = (half * 2) * 1024 + r * 8;
    const int j1 = j0 + 1024;
#pragma unroll
    for (int e = 0; e < 8; ++e) {
        sh[j0 + e] = h[e];     sl[j0 + e] = l[e];
        sh[j1 + e] = h[8 + e]; sl[j1 + e] = l[8 + e];
    }
    __syncthreads();
    const size_t og = ((size_t)R * NKT + kt) * 4096;
    *(f16x8*)&ph[og + t * 8]        = *(const f16x8*)&sh[t * 8];
    *(f16x8*)&ph[og + 2048 + t * 8] = *(const f16x8*)&sh[2048 + t * 8];
    *(f16x8*)&pl[og + t * 8]        = *(const f16x8*)&sl[t * 8];
    *(f16x8*)&pl[og + 2048 + t * 8] = *(const f16x8*)&sl[2048 + t * 8];
}

// ---------------- K0: centroid, two-stage deterministic ----------------
__global__ void centroid_part_kernel(const float* __restrict__ w, float* __restrict__ part) {
    const int c = blockIdx.x * 256 + threadIdx.x;
    const int seg = blockIdx.y;
    const int l0 = seg * (LS / NSEG);
    float acc = 0.f;
    for (int l = 0; l < LS / NSEG; ++l)
        acc += w[(size_t)(l0 + l) * DF + c];
    part[(size_t)seg * DF + c] = acc;
}

__global__ void centroid_sum_kernel(const float* __restrict__ part, float* __restrict__ cen) {
    const int c = blockIdx.x * 256 + threadIdx.x;
    float acc = 0.f;
    for (int s = 0; s < NSEG; ++s) acc += part[(size_t)s * DF + c];
    cen[c] = acc * (1.0f / (float)LS);
}

// ---------------- K1: S = x @ w^T, 3-term f16-split, 32x32x16 MFMA ----------------
// CHAMPION (r16): packed-plane global staging (contiguous 1 KB wave bursts),
// linear LDS image = conflict-free plane layout (SQ_LDS_BANK_CONFLICT = 0),
// 2 __syncthreads per kt, register-fragment prefetch. 32 KB LDS, VGPR 80,
// default blockIdx mapping (XCD swizzle measured -5%: dispatcher locality wins).
#define GLOAD16(gptr, lptr)                                                    \
    __builtin_amdgcn_global_load_lds(                                          \
        (const __attribute__((address_space(1))) void*)(gptr),                 \
        (__attribute__((address_space(3))) void*)(lptr), 16, 0, 0)

__global__ __launch_bounds__(256) void gemm_f16_kernel(
    const f16* __restrict__ xph, const f16* __restrict__ xpl,
    const f16* __restrict__ wph, const f16* __restrict__ wpl,
    float* __restrict__ S, int r0, int rowsChunk)
{
    __shared__ __align__(16) f16 Ah[4096];   // plane image, 8 KB
    __shared__ __align__(16) f16 Al[4096];
    __shared__ __align__(16) f16 Bh[4096];
    __shared__ __align__(16) f16 Bl[4096];

    const int t = threadIdx.x;
    const int lane = t & 63;
    const int wv = t >> 6;                 // wave id 0..3
    const int wr = (wv >> 1) * 64;         // wave row offset in tile
    const int wc = (wv & 1) * 64;          // wave col offset in tile

    f32x16 acc[2][2];
#pragma unroll
    for (int m = 0; m < 2; ++m)
#pragma unroll
        for (int n = 0; n < 2; ++n)
#pragma unroll
            for (int j = 0; j < 16; ++j) acc[m][n][j] = 0.f;

    const int c32 = lane & 31;             // row/col within a 32x32 frag
    const int kh = lane >> 5;              // k-half -> plane parity

    const size_t atile = ((size_t)((r0 >> 7) + blockIdx.y)) * NKT;
    const size_t btile = ((size_t)blockIdx.x) * NKT;
    const int lb0 = wv * 512;              // f16 offset, issue0
    const int lb1 = 2048 + wv * 512;       // issue1

#define STAGE(kt)                                                          \
    do {                                                                   \
        const size_t _a = (atile + (kt)) * 4096 + t * 8;                   \
        const size_t _b = (btile + (kt)) * 4096 + t * 8;                   \
        GLOAD16(xph + _a,        &Ah[lb0]);                                \
        GLOAD16(xph + _a + 2048, &Ah[lb1]);                                \
        GLOAD16(xpl + _a,        &Al[lb0]);                                \
        GLOAD16(xpl + _a + 2048, &Al[lb1]);                                \
        GLOAD16(wph + _b,        &Bh[lb0]);                                \
        GLOAD16(wph + _b + 2048, &Bh[lb1]);                                \
        GLOAD16(wpl + _b,        &Bl[lb0]);                                \
        GLOAD16(wpl + _b + 2048, &Bl[lb1]);                                \
    } while (0)

    STAGE(0);

    for (int kt = 0; kt < NKT; ++kt) {
        // barrier #1: implicit vmcnt(0) — kt's DMA issued a full MFMA phase ago.
        __syncthreads();

        // ---- all fragments of kt -> registers (16 x ds_read_b128, zero
        //      bank conflicts — r13/r16-proven plane layout) ----
        f16x8 amh[2][2], aml[2][2], bnh[2][2], bnl[2][2];  // [slice][frag]
#pragma unroll
        for (int s = 0; s < 2; ++s) {
            const int pl = s * 2 + kh;     // plane
#pragma unroll
            for (int m = 0; m < 2; ++m) {
                const int j = pl * 1024 + (wr + m * 32 + c32) * 8;
                amh[s][m] = *(const f16x8*)&Ah[j];
                aml[s][m] = *(const f16x8*)&Al[j];
            }
#pragma unroll
            for (int n = 0; n < 2; ++n) {
                const int j = pl * 1024 + (wc + n * 32 + c32) * 8;
                bnh[s][n] = *(const f16x8*)&Bh[j];
                bnl[s][n] = *(const f16x8*)&Bl[j];
            }
        }

        // barrier #2: implicit lgkmcnt(0) — all waves done reading; LDS free.
        __syncthreads();
        if (kt + 1 < NKT) STAGE(kt + 1);   // DMA flies under the MFMAs

        // ---- 24 MFMA on registers ----
#pragma unroll
        for (int s = 0; s < 2; ++s)
#pragma unroll
            for (int m = 0; m < 2; ++m)
#pragma unroll
                for (int n = 0; n < 2; ++n) {
                    acc[m][n] = __builtin_amdgcn_mfma_f32_32x32x16_f16(amh[s][m], bnh[s][n], acc[m][n], 0, 0, 0);
                    acc[m][n] = __builtin_amdgcn_mfma_f32_32x32x16_f16(amh[s][m], bnl[s][n], acc[m][n], 0, 0, 0);
                    acc[m][n] = __builtin_amdgcn_mfma_f32_32x32x16_f16(aml[s][m], bnh[s][n], acc[m][n], 0, 0, 0);
                }
    }
#undef STAGE

    // C write: col = lane&31, row = (reg&3) + 8*(reg>>2) + 4*(lane>>5)  [m74/m101]
#pragma unroll
    for (int m = 0; m < 2; ++m) {
        const int rb = blockIdx.y * BM + wr + m * 32 + 4 * kh;   // chunk-local
#pragma unroll
        for (int n = 0; n < 2; ++n) {
            const int cc = blockIdx.x * BN + wc + n * 32 + c32;
#pragma unroll
            for (int reg = 0; reg < 16; ++reg) {
                const int rr = rb + (reg & 3) + 8 * (reg >> 2);
                if (rr < rowsChunk)
                    S[(size_t)rr * LS + cc] = acc[m][n][reg];
            }
        }
    }
}

// ---------------- K2: per-row softmax/shrink/norm + all outputs (float4) ----------------
__global__ __launch_bounds__(256) void pass2_kernel(
    const float* __restrict__ S, const float* __restrict__ x,
    const float* __restrict__ w, const float* __restrict__ cen,
    float* __restrict__ out, int r0)
{
    constexpr int T = 256;
    __shared__ __align__(16) float att_lds[LS];
    __shared__ float red[T];
    __shared__ int redi[T];

    const int t = threadIdx.x;
    const size_t row = (size_t)r0 + blockIdx.x;
    const float4* s4 = (const float4*)(S + (size_t)blockIdx.x * (size_t)LS);

    float* const out_output = out;
    float* const out_att  = out + (size_t)NS * DF;
    float* const out_nl   = out + (size_t)NS * DF + (size_t)NS * LS;
    float* const out_nl2  = out + (size_t)2 * NS * DF + (size_t)NS * LS;
    float* const out_mask = out + (size_t)3 * NS * DF + (size_t)NS * LS;

    float sv[16];
    float mx = -INFINITY;
#pragma unroll
    for (int i = 0; i < 4; ++i) {
        float4 v = s4[i * 256 + t];
        sv[i * 4 + 0] = v.x; sv[i * 4 + 1] = v.y;
        sv[i * 4 + 2] = v.z; sv[i * 4 + 3] = v.w;
        mx = fmaxf(mx, fmaxf(fmaxf(v.x, v.y), fmaxf(v.z, v.w)));
    }
    red[t] = mx;
    __syncthreads();
    for (int off = 128; off >= 1; off >>= 1) {
        if (t < off) red[t] = fmaxf(red[t], red[t + off]);
        __syncthreads();
    }
    const float m = red[0];
    __syncthreads();

    float zs = 0.f;
#pragma unroll
    for (int i = 0; i < 16; ++i) {
        sv[i] = expf(sv[i] - m);
        zs += sv[i];
    }
    red[t] = zs;
    __syncthreads();
    for (int off = 128; off >= 1; off >>= 1) {
        if (t < off) red[t] += red[t + off];
        __syncthreads();
    }
    const float Z = red[0];
    __syncthreads();

    float l1 = 0.f;
#pragma unroll
    for (int i = 0; i < 16; ++i) {
        float a = sv[i] / Z;
        float r = a - SHRINK_T;
        float v = (r > 0.f) ? (r * a) / (r + EPS_T) : 0.f;
        sv[i] = v;
        l1 += v;
    }
    red[t] = l1;
    __syncthreads();
    for (int off = 128; off >= 1; off >>= 1) {
        if (t < off) red[t] += red[t + off];
        __syncthreads();
    }
    const float nrm = fmaxf(red[0], EPS_T);
    __syncthreads();

    float bv = -INFINITY; int bi = LS;
    float mn = INFINITY;
    float4* const attl4 = (float4*)att_lds;
    float4* const att4o = (float4*)(out_att + row * LS);
#pragma unroll
    for (int i = 0; i < 4; ++i) {
        float4 vn4;
        vn4.x = sv[i * 4 + 0] / nrm; vn4.y = sv[i * 4 + 1] / nrm;
        vn4.z = sv[i * 4 + 2] / nrm; vn4.w = sv[i * 4 + 3] / nrm;
        sv[i * 4 + 0] = vn4.x; sv[i * 4 + 1] = vn4.y;
        sv[i * 4 + 2] = vn4.z; sv[i * 4 + 3] = vn4.w;
        attl4[i * 256 + t] = vn4;
        att4o[i * 256 + t] = vn4;
#pragma unroll
        for (int c = 0; c < 4; ++c) {
            const float v = sv[i * 4 + c];
            const int j = i * 1024 + 4 * t + c;
            if (v > bv) { bv = v; bi = j; }
            mn = fminf(mn, v);
        }
    }
    __syncthreads();

    red[t] = bv; redi[t] = bi;
    __syncthreads();
    for (int off = 128; off >= 1; off >>= 1) {
        if (t < off) {
            float ov = red[t + off]; int oi = redi[t + off];
            if (ov > red[t] || (ov == red[t] && oi < redi[t])) { red[t] = ov; redi[t] = oi; }
        }
        __syncthreads();
    }
    const int ind = redi[0];
    __syncthreads();

    red[t] = mn;
    __syncthreads();
    for (int off = 128; off >= 1; off >>= 1) {
        if (t < off) red[t] = fminf(red[t], red[t + off]);
        __syncthreads();
    }
    const float rowmin = red[0];
    __syncthreads();

    bv = -INFINITY; bi = LS;
#pragma unroll
    for (int i = 0; i < 4; ++i)
#pragma unroll
        for (int c = 0; c < 4; ++c) {
            const int j = i * 1024 + 4 * t + c;
            const float vv = (j == ind) ? rowmin : sv[i * 4 + c];
            if (vv > bv) { bv = vv; bi = j; }
        }
    red[t] = bv; redi[t] = bi;
    __syncthreads();
    for (int off = 128; off >= 1; off >>= 1) {
        if (t < off) {
            float ov = red[t + off]; int oi = redi[t + off];
            if (ov > red[t] || (ov == red[t] && oi < redi[t])) { red[t] = ov; redi[t] = oi; }
        }
        __syncthreads();
    }
    const int ind2 = redi[0];
    __syncthreads();

    const int lane = t & 63;
    float4 oa = {0.f, 0.f, 0.f, 0.f};
    for (int k0 = 0; k0 < LS; k0 += 64) {
        float av = att_lds[k0 + lane];
        unsigned long long msk = __ballot(av > 0.f);
        while (msk) {
            int b = __ffsll((unsigned long long)msk) - 1;
            msk &= msk - 1;
            float vv = att_lds[k0 + b];
            float4 wv4 = ((const float4*)(w + (size_t)(k0 + b) * DF))[t];
            oa.x = fmaf(vv, wv4.x, oa.x);
            oa.y = fmaf(vv, wv4.y, oa.y);
            oa.z = fmaf(vv, wv4.z, oa.z);
            oa.w = fmaf(vv, wv4.w, oa.w);
        }
    }
    ((float4*)(out_output + row * DF))[t] = oa;

    ((float4*)(out_nl  + row * DF))[t] = ((const float4*)(w + (size_t)ind  * DF))[t];
    ((float4*)(out_nl2 + row * DF))[t] = ((const float4*)(w + (size_t)ind2 * DF))[t];

    float4 xv = ((const float4*)(x + row * DF))[t];
    float4 cv = ((const float4*)cen)[t];
    float ds = 0.f;
    ds = fmaf(xv.x - cv.x, xv.x - cv.x, ds);
    ds = fmaf(xv.y - cv.y, xv.y - cv.y, ds);
    ds = fmaf(xv.z - cv.z, xv.z - cv.z, ds);
    ds = fmaf(xv.w - cv.w, xv.w - cv.w, ds);
    red[t] = ds;
    __syncthreads();
    for (int off = 128; off >= 1; off >>= 1) {
        if (t < off) red[t] += red[t + off];
        __syncthreads();
    }
    if (t == 0) {
        float dist = sqrtf(red[0]);
        out_mask[row] = (dist < 1.0f) ? 1.0f : 0.0f;
    }
}

// ---------------- host ----------------
extern "C" void kernel_launch(void* const* d_in, const int* in_sizes, int n_in,
                              void* d_out, int out_size, void* d_ws, size_t ws_size,
                              hipStream_t stream)
{
    const float* x = (const float*)d_in[0];
    const float* w = (const float*)d_in[1];
    float* out = (float*)d_out;

    // workspace layout: cen | partial | xph | xpl | wph | wpl | S
    float* cen = (float*)d_ws;
    float* part = cen + DF;
    f16* xph = (f16*)(part + (size_t)NSEG * DF);
    f16* xpl = xph + (size_t)NS * DF;
    f16* wph = xpl + (size_t)NS * DF;
    f16* wpl = wph + (size_t)LS * DF;
    float* S = (float*)(wpl + (size_t)LS * DF);

    const size_t head_bytes = sizeof(float) * (DF + (size_t)NSEG * DF)
                            + (size_t)2 * 2 * NS * DF + (size_t)2 * 2 * LS * DF;
    long cap_rows = (long)((ws_size - head_bytes) / (sizeof(float) * LS));
    if (cap_rows > NS) cap_rows = NS;
    if (cap_rows < 1) cap_rows = 1;
    int chunk = (cap_rows >= BM) ? (int)(cap_rows - (cap_rows % BM)) : (int)cap_rows;

    centroid_part_kernel<<<dim3(DF / 256, NSEG), 256, 0, stream>>>(w, part);
    centroid_sum_kernel<<<DF / 256, 256, 0, stream>>>(part, cen);
    pack_kernel<<<dim3(NKT, NS / 128), 256, 0, stream>>>(x, xph, xpl);
    pack_kernel<<<dim3(NKT, LS / 128), 256, 0, stream>>>(w, wph, wpl);

    for (int r0 = 0; r0 < NS; r0 += chunk) {
        int rows = (NS - r0 < chunk) ? (NS - r0) : chunk;
        dim3 grid(LS / BN, (rows + BM - 1) / BM);
        gemm_f16_kernel<<<grid, 256, 0, stream>>>(xph, xpl, wph, wpl, S, r0, rows);
        pass2_kernel<<<rows, 256, 0, stream>>>(S, x, w, cen, out, r0);
    }
}